// Round 5
// baseline (297.739 us; speedup 1.0000x reference)
//
#include <hip/hip_runtime.h>

#define NB 2
#define DD 480
#define HH 360
#define WD 32
#define CIN 16
#define COUT 32
#define EPSV 1e-5f
#define NEGS 0.01f

__global__ __launch_bounds__(256) void scatter_grid(const int* __restrict__ coords,
                                                    int* __restrict__ grid, int n) {
    int i = blockIdx.x * 256 + threadIdx.x;
    if (i >= n) return;
    int b = coords[i * 4 + 0];
    int z = coords[i * 4 + 1];
    int y = coords[i * 4 + 2];
    int x = coords[i * 4 + 3];
    grid[(((size_t)b * DD + z) * HH + y) * WD + x] = i;
}

// Compact non-center valid taps per point. Center tap (k=4) is always the
// point itself. ent entries: (k<<24) | j   (j < 2^24 since n = 200000)
__global__ __launch_bounds__(256) void build_nbr_compact(
    const int* __restrict__ coords, const int* __restrict__ grid,
    int* __restrict__ cnt133, int* __restrict__ ent133,
    int* __restrict__ cnt313, int* __restrict__ ent313, int n) {
    int i = blockIdx.x * 256 + threadIdx.x;
    if (i >= n) return;
    int b = coords[i * 4 + 0];
    int z = coords[i * 4 + 1];
    int y = coords[i * 4 + 2];
    int x = coords[i * 4 + 3];
    size_t base_b = (size_t)b * DD;
    int c1 = 0, c2 = 0;
#pragma unroll
    for (int k = 0; k < 9; ++k) {
        if (k == 4) continue;
        int d0 = k / 3 - 1;  // dy for 133, dz for 313
        int dx = k % 3 - 1;
        int nx = x + dx;
        bool xok = (nx >= 0) && (nx < WD);
        int ny = y + d0;
        if (xok && ny >= 0 && ny < HH) {
            int j = grid[((base_b + z) * HH + ny) * WD + nx];
            if (j >= 0) { ent133[(size_t)c1 * n + i] = (k << 24) | j; ++c1; }
        }
        int nz = z + d0;
        if (xok && nz >= 0 && nz < DD) {
            int j = grid[((base_b + nz) * HH + y) * WD + nx];
            if (j >= 0) { ent313[(size_t)c2 * n + i] = (k << 24) | j; ++c2; }
        }
    }
    cnt133[i] = c1;
    cnt313[i] = c2;
}

// Fold BN scale into weights once per call.
// Ws layout (floats): conv1 [9][16][32] @ 0, conv2 [9][32][32] @ 4608,
//                     conv3 [9][16][32] @ 13824, conv4 [9][32][32] @ 18432
__global__ __launch_bounds__(256) void prep_weights(
    const float* __restrict__ W1, const float* __restrict__ W2,
    const float* __restrict__ W3, const float* __restrict__ W4,
    const float* __restrict__ gamma, const float* __restrict__ beta,
    const float* __restrict__ mean, const float* __restrict__ var,
    float* __restrict__ Ws, float* __restrict__ sh) {
    int t = blockIdx.x * 256 + threadIdx.x;
    if (t < 4 * COUT) {
        float s = gamma[t] * rsqrtf(var[t] + EPSV);
        sh[t] = beta[t] - mean[t] * s;
    }
    if (t >= 27648) return;
    const float* src;
    int loc, bn;
    if (t < 4608)       { src = W1; loc = t;         bn = 0; }
    else if (t < 13824) { src = W2; loc = t - 4608;  bn = 1; }
    else if (t < 18432) { src = W3; loc = t - 13824; bn = 2; }
    else                { src = W4; loc = t - 18432; bn = 3; }
    int co = loc & 31;
    float s = gamma[bn * COUT + co] * rsqrtf(var[bn * COUT + co] + EPSV);
    Ws[t] = src[loc] * s;
}

// Fused pair of independent sparse convs. Center-tap weights in LDS
// (2-4 KB, wave-uniform broadcast reads); rare extras read weights
// per-lane from global (L2-hot 108 KB region). 2 points per thread for
// FMA ILP and to amortize LDS weight reads.
template <int CI>
__global__ __launch_bounds__(256) void conv_pair(
    const float* __restrict__ in0, const int* __restrict__ cnt0,
    const int* __restrict__ ent0, const float* __restrict__ Ws0,
    const float* __restrict__ sh0, float* __restrict__ out0,
    const float* __restrict__ in1, const int* __restrict__ cnt1,
    const int* __restrict__ ent1, const float* __restrict__ Ws1,
    const float* __restrict__ sh1, float* __restrict__ out1,
    int n, int nblk) {
    __shared__ float Wc[CI * COUT];  // center-tap weights only
    int tid = threadIdx.x;
    bool second = (int)blockIdx.x >= nblk;
    const float* in  = second ? in1 : in0;
    const int* cnt   = second ? cnt1 : cnt0;
    const int* ent   = second ? ent1 : ent0;
    const float* Ws  = second ? Ws1 : Ws0;
    const float* sh  = second ? sh1 : sh0;
    float* out       = second ? out1 : out0;

    {
        const float4* wg4 = (const float4*)(Ws + 4 * CI * COUT);
        float4* wl4 = (float4*)Wc;
        for (int t = tid; t < CI * COUT / 4; t += 256) wl4[t] = wg4[t];
    }
    __syncthreads();

    int ib = second ? (int)blockIdx.x - nblk : (int)blockIdx.x;
    int p0 = ib * 512 + tid;
    int p1 = p0 + 256;
    bool v1ok = p1 < n;
    if (p0 >= n) return;
    int pb = v1ok ? p1 : p0;

    float acc0[COUT], acc1[COUT];
    const float4* sh4 = (const float4*)sh;
#pragma unroll
    for (int c4 = 0; c4 < COUT / 4; ++c4) {
        float4 s = sh4[c4];
        acc0[c4 * 4 + 0] = s.x; acc0[c4 * 4 + 1] = s.y;
        acc0[c4 * 4 + 2] = s.z; acc0[c4 * 4 + 3] = s.w;
        acc1[c4 * 4 + 0] = s.x; acc1[c4 * 4 + 1] = s.y;
        acc1[c4 * 4 + 2] = s.z; acc1[c4 * 4 + 3] = s.w;
    }

    // ---- center tap: LDS broadcast weights, 2 points share each weight read
    {
        const float4* fa = (const float4*)(in + (size_t)p0 * CI);
        const float4* fb = (const float4*)(in + (size_t)pb * CI);
#pragma unroll
        for (int q = 0; q < CI / 4; ++q) {
            float4 va = fa[q];
            float4 vb = fb[q];
            const float* w = &Wc[q * 4 * COUT];
#pragma unroll
            for (int c4 = 0; c4 < COUT / 4; ++c4) {
                float4 w0 = *(const float4*)&w[0 * COUT + c4 * 4];
                float4 w1 = *(const float4*)&w[1 * COUT + c4 * 4];
                float4 w2 = *(const float4*)&w[2 * COUT + c4 * 4];
                float4 w3 = *(const float4*)&w[3 * COUT + c4 * 4];
                acc0[c4 * 4 + 0] += va.x * w0.x + va.y * w1.x + va.z * w2.x + va.w * w3.x;
                acc0[c4 * 4 + 1] += va.x * w0.y + va.y * w1.y + va.z * w2.y + va.w * w3.y;
                acc0[c4 * 4 + 2] += va.x * w0.z + va.y * w1.z + va.z * w2.z + va.w * w3.z;
                acc0[c4 * 4 + 3] += va.x * w0.w + va.y * w1.w + va.z * w2.w + va.w * w3.w;
                acc1[c4 * 4 + 0] += vb.x * w0.x + vb.y * w1.x + vb.z * w2.x + vb.w * w3.x;
                acc1[c4 * 4 + 1] += vb.x * w0.y + vb.y * w1.y + vb.z * w2.y + vb.w * w3.y;
                acc1[c4 * 4 + 2] += vb.x * w0.z + vb.y * w1.z + vb.z * w2.z + vb.w * w3.z;
                acc1[c4 * 4 + 3] += vb.x * w0.w + vb.y * w1.w + vb.z * w2.w + vb.w * w3.w;
            }
        }
    }

    // ---- rare extras (avg ~0.14/point): per-lane weight loads from global
#pragma unroll 1
    for (int half = 0; half < 2; ++half) {
        int p = half ? p1 : p0;
        if (half && !v1ok) break;
        float* acc = half ? acc1 : acc0;
        int cn = cnt[p];
#pragma unroll 1
        for (int m = 0; m < cn; ++m) {
            int e = ent[(size_t)m * n + p];
            int k = e >> 24;
            int j = e & 0xFFFFFF;
            const float4* g4 = (const float4*)(in + (size_t)j * CI);
            const float* wk = Ws + k * CI * COUT;
#pragma unroll
            for (int q = 0; q < CI / 4; ++q) {
                float4 v = g4[q];
#pragma unroll
                for (int e4 = 0; e4 < 4; ++e4) {
                    float fe = (e4 == 0) ? v.x : (e4 == 1) ? v.y : (e4 == 2) ? v.z : v.w;
                    const float4* wr = (const float4*)(wk + (q * 4 + e4) * COUT);
#pragma unroll
                    for (int c4 = 0; c4 < COUT / 4; ++c4) {
                        float4 w = wr[c4];
                        acc[c4 * 4 + 0] += fe * w.x;
                        acc[c4 * 4 + 1] += fe * w.y;
                        acc[c4 * 4 + 2] += fe * w.z;
                        acc[c4 * 4 + 3] += fe * w.w;
                    }
                }
            }
        }
    }

    float4* o0 = (float4*)(out + (size_t)p0 * COUT);
#pragma unroll
    for (int c4 = 0; c4 < COUT / 4; ++c4) {
        float4 r;
        r.x = acc0[4 * c4 + 0]; r.y = acc0[4 * c4 + 1];
        r.z = acc0[4 * c4 + 2]; r.w = acc0[4 * c4 + 3];
        r.x = (r.x >= 0.f) ? r.x : NEGS * r.x;
        r.y = (r.y >= 0.f) ? r.y : NEGS * r.y;
        r.z = (r.z >= 0.f) ? r.z : NEGS * r.z;
        r.w = (r.w >= 0.f) ? r.w : NEGS * r.w;
        o0[c4] = r;
    }
    if (v1ok) {
        float4* o1 = (float4*)(out + (size_t)p1 * COUT);
#pragma unroll
        for (int c4 = 0; c4 < COUT / 4; ++c4) {
            float4 r;
            r.x = acc1[4 * c4 + 0]; r.y = acc1[4 * c4 + 1];
            r.z = acc1[4 * c4 + 2]; r.w = acc1[4 * c4 + 3];
            r.x = (r.x >= 0.f) ? r.x : NEGS * r.x;
            r.y = (r.y >= 0.f) ? r.y : NEGS * r.y;
            r.z = (r.z >= 0.f) ? r.z : NEGS * r.z;
            r.w = (r.w >= 0.f) ? r.w : NEGS * r.w;
            o1[c4] = r;
        }
    }
}

__global__ __launch_bounds__(256) void add_res(float* __restrict__ out,
                                               const float* __restrict__ s, int n4) {
    int i = blockIdx.x * 256 + threadIdx.x;
    if (i < n4) {
        float4 a = ((const float4*)out)[i];
        float4 b = ((const float4*)s)[i];
        a.x += b.x; a.y += b.y; a.z += b.z; a.w += b.w;
        ((float4*)out)[i] = a;
    }
}

extern "C" void kernel_launch(void* const* d_in, const int* in_sizes, int n_in,
                              void* d_out, int out_size, void* d_ws, size_t ws_size,
                              hipStream_t stream) {
    const float* feats = (const float*)d_in[0];
    const int* coords  = (const int*)d_in[1];
    const float* W1    = (const float*)d_in[2];
    const float* W2    = (const float*)d_in[3];
    const float* W3    = (const float*)d_in[4];
    const float* W4    = (const float*)d_in[5];
    const float* gamma = (const float*)d_in[6];
    const float* beta  = (const float*)d_in[7];
    const float* mean  = (const float*)d_in[8];
    const float* var   = (const float*)d_in[9];

    int n = in_sizes[0] / CIN;  // 200000

    char* ws = (char*)d_ws;
    size_t cntBytes  = (size_t)n * sizeof(int);
    size_t entBytes  = (size_t)8 * n * sizeof(int);
    size_t wsBytes   = (size_t)27648 * sizeof(float);
    size_t shBytes   = (size_t)128 * sizeof(float);
    size_t featBytes = (size_t)n * COUT * sizeof(float);
    size_t gridBytes = (size_t)NB * DD * HH * WD * sizeof(int);

    int* cnt133 = (int*)ws;
    int* cnt313 = (int*)(ws + cntBytes);
    int* ent133 = (int*)(ws + 2 * cntBytes);
    int* ent313 = (int*)(ws + 2 * cntBytes + entBytes);
    float* Wsc  = (float*)(ws + 2 * cntBytes + 2 * entBytes);
    float* shv  = (float*)(ws + 2 * cntBytes + 2 * entBytes + wsBytes);
    char* fbase = ws + 2 * cntBytes + 2 * entBytes + wsBytes + shBytes;
    float* s1 = (float*)fbase;                      // conv1 out
    float* s2 = (float*)(fbase + featBytes);        // shortcut
    float* r1 = (float*)(fbase + 2 * featBytes);    // conv3 out
    int* grid = (int*)fbase;  // overlaps s1/s2 region; grid dead after build_nbr

    int nblk = (n + 255) / 256;
    int nblk2 = (n + 511) / 512;

    prep_weights<<<(27648 + 255) / 256, 256, 0, stream>>>(
        W1, W2, W3, W4, gamma, beta, mean, var, Wsc, shv);
    hipMemsetAsync(grid, 0xFF, gridBytes, stream);
    scatter_grid<<<nblk, 256, 0, stream>>>(coords, grid, n);
    build_nbr_compact<<<nblk, 256, 0, stream>>>(coords, grid, cnt133, ent133,
                                                cnt313, ent313, n);

    // conv1 (feats->s1, bn0) || conv3 (feats->r1, bn2)
    conv_pair<CIN><<<2 * nblk2, 256, 0, stream>>>(
        feats, cnt133, ent133, Wsc + 0,     shv + 0 * COUT, s1,
        feats, cnt313, ent313, Wsc + 13824, shv + 2 * COUT, r1,
        n, nblk2);

    // conv2 (s1->s2, bn1) || conv4 (r1->d_out, bn3)
    conv_pair<COUT><<<2 * nblk2, 256, 0, stream>>>(
        s1, cnt313, ent313, Wsc + 4608,  shv + 1 * COUT, s2,
        r1, cnt133, ent133, Wsc + 18432, shv + 3 * COUT, (float*)d_out,
        n, nblk2);

    // d_out += s2 (resA + shortcut)
    int n4 = n * COUT / 4;
    add_res<<<(n4 + 255) / 256, 256, 0, stream>>>((float*)d_out, s2, n4);
}

// Round 6
// 247.402 us; speedup vs baseline: 1.2035x; 1.2035x over previous
//
#include <hip/hip_runtime.h>

#define NB 2
#define DD 480
#define HH 360
#define WD 32
#define CIN 16
#define COUT 32
#define EPSV 1e-5f
#define NEGS 0.01f

__global__ __launch_bounds__(256) void scatter_grid(const int* __restrict__ coords,
                                                    int* __restrict__ grid, int n) {
    int i = blockIdx.x * 256 + threadIdx.x;
    if (i >= n) return;
    int b = coords[i * 4 + 0];
    int z = coords[i * 4 + 1];
    int y = coords[i * 4 + 2];
    int x = coords[i * 4 + 3];
    grid[(((size_t)b * DD + z) * HH + y) * WD + x] = i;
}

// Compact non-center valid taps per point. Center tap (k=4) is always the
// point itself. ent entries: (k<<24) | j   (j < 2^24 since n = 200000)
__global__ __launch_bounds__(256) void build_nbr_compact(
    const int* __restrict__ coords, const int* __restrict__ grid,
    int* __restrict__ cnt133, int* __restrict__ ent133,
    int* __restrict__ cnt313, int* __restrict__ ent313, int n) {
    int i = blockIdx.x * 256 + threadIdx.x;
    if (i >= n) return;
    int b = coords[i * 4 + 0];
    int z = coords[i * 4 + 1];
    int y = coords[i * 4 + 2];
    int x = coords[i * 4 + 3];
    size_t base_b = (size_t)b * DD;
    int c1 = 0, c2 = 0;
#pragma unroll
    for (int k = 0; k < 9; ++k) {
        if (k == 4) continue;
        int d0 = k / 3 - 1;  // dy for 133, dz for 313
        int dx = k % 3 - 1;
        int nx = x + dx;
        bool xok = (nx >= 0) && (nx < WD);
        int ny = y + d0;
        if (xok && ny >= 0 && ny < HH) {
            int j = grid[((base_b + z) * HH + ny) * WD + nx];
            if (j >= 0) { ent133[(size_t)c1 * n + i] = (k << 24) | j; ++c1; }
        }
        int nz = z + d0;
        if (xok && nz >= 0 && nz < DD) {
            int j = grid[((base_b + nz) * HH + y) * WD + nx];
            if (j >= 0) { ent313[(size_t)c2 * n + i] = (k << 24) | j; ++c2; }
        }
    }
    cnt133[i] = c1;
    cnt313[i] = c2;
}

// Fold BN scale into weights once per call.
// Ws layout (floats): conv1 [9][16][32] @ 0, conv2 [9][32][32] @ 4608,
//                     conv3 [9][16][32] @ 13824, conv4 [9][32][32] @ 18432
__global__ __launch_bounds__(256) void prep_weights(
    const float* __restrict__ W1, const float* __restrict__ W2,
    const float* __restrict__ W3, const float* __restrict__ W4,
    const float* __restrict__ gamma, const float* __restrict__ beta,
    const float* __restrict__ mean, const float* __restrict__ var,
    float* __restrict__ Ws, float* __restrict__ sh) {
    int t = blockIdx.x * 256 + threadIdx.x;
    if (t < 4 * COUT) {
        float s = gamma[t] * rsqrtf(var[t] + EPSV);
        sh[t] = beta[t] - mean[t] * s;
    }
    if (t >= 27648) return;
    const float* src;
    int loc, bn;
    if (t < 4608)       { src = W1; loc = t;         bn = 0; }
    else if (t < 13824) { src = W2; loc = t - 4608;  bn = 1; }
    else if (t < 18432) { src = W3; loc = t - 13824; bn = 2; }
    else                { src = W4; loc = t - 18432; bn = 3; }
    int co = loc & 31;
    float s = gamma[bn * COUT + co] * rsqrtf(var[bn * COUT + co] + EPSV);
    Ws[t] = src[loc] * s;
}

// Fused pair of independent sparse convs. R3 datapath (1 point/thread,
// LDS-broadcast center weights) but LDS holds ONLY the center tap
// (2-4 KB) so occupancy is VGPR-capped, not LDS-capped. Rare extras
// (~0.14/point) read weights per-lane from global (L2-hot).
template <int CI>
__global__ __launch_bounds__(256) void conv_pair(
    const float* __restrict__ in0, const int* __restrict__ cnt0,
    const int* __restrict__ ent0, const float* __restrict__ Ws0,
    const float* __restrict__ sh0, float* __restrict__ out0,
    const float* __restrict__ in1, const int* __restrict__ cnt1,
    const int* __restrict__ ent1, const float* __restrict__ Ws1,
    const float* __restrict__ sh1, float* __restrict__ out1,
    int n, int nblk) {
    __shared__ float Wc[CI * COUT];  // center-tap weights only
    int tid = threadIdx.x;
    bool second = (int)blockIdx.x >= nblk;
    const float* in  = second ? in1 : in0;
    const int* cnt   = second ? cnt1 : cnt0;
    const int* ent   = second ? ent1 : ent0;
    const float* Ws  = second ? Ws1 : Ws0;
    const float* sh  = second ? sh1 : sh0;
    float* out       = second ? out1 : out0;

    {
        const float4* wg4 = (const float4*)(Ws + 4 * CI * COUT);
        float4* wl4 = (float4*)Wc;
        for (int t = tid; t < CI * COUT / 4; t += 256) wl4[t] = wg4[t];
    }
    __syncthreads();

    int ib = second ? (int)blockIdx.x - nblk : (int)blockIdx.x;
    int i = ib * 256 + tid;
    if (i >= n) return;

    float acc[COUT];
    const float4* sh4 = (const float4*)sh;
#pragma unroll
    for (int c4 = 0; c4 < COUT / 4; ++c4) {
        float4 s = sh4[c4];
        acc[c4 * 4 + 0] = s.x; acc[c4 * 4 + 1] = s.y;
        acc[c4 * 4 + 2] = s.z; acc[c4 * 4 + 3] = s.w;
    }

    // ---- center tap: LDS broadcast weights (uniform address, conflict-free)
    {
        const float4* f4 = (const float4*)(in + (size_t)i * CI);
#pragma unroll
        for (int q = 0; q < CI / 4; ++q) {
            float4 v = f4[q];
            const float* w = &Wc[q * 4 * COUT];
#pragma unroll
            for (int c4 = 0; c4 < COUT / 4; ++c4) {
                float4 w0 = *(const float4*)&w[0 * COUT + c4 * 4];
                float4 w1 = *(const float4*)&w[1 * COUT + c4 * 4];
                float4 w2 = *(const float4*)&w[2 * COUT + c4 * 4];
                float4 w3 = *(const float4*)&w[3 * COUT + c4 * 4];
                acc[c4 * 4 + 0] += v.x * w0.x + v.y * w1.x + v.z * w2.x + v.w * w3.x;
                acc[c4 * 4 + 1] += v.x * w0.y + v.y * w1.y + v.z * w2.y + v.w * w3.y;
                acc[c4 * 4 + 2] += v.x * w0.z + v.y * w1.z + v.z * w2.z + v.w * w3.z;
                acc[c4 * 4 + 3] += v.x * w0.w + v.y * w1.w + v.z * w2.w + v.w * w3.w;
            }
        }
    }

    // ---- rare extras (~0.14/point): per-lane weight loads from global (L2-hot)
    int cn = cnt[i];
#pragma unroll 1
    for (int m = 0; m < cn; ++m) {
        int e = ent[(size_t)m * n + i];
        int k = e >> 24;
        int j = e & 0xFFFFFF;
        const float4* g4 = (const float4*)(in + (size_t)j * CI);
        const float* wk = Ws + k * CI * COUT;
#pragma unroll
        for (int q = 0; q < CI / 4; ++q) {
            float4 v = g4[q];
#pragma unroll
            for (int e4 = 0; e4 < 4; ++e4) {
                float fe = (e4 == 0) ? v.x : (e4 == 1) ? v.y : (e4 == 2) ? v.z : v.w;
                const float4* wr = (const float4*)(wk + (q * 4 + e4) * COUT);
#pragma unroll
                for (int c4 = 0; c4 < COUT / 4; ++c4) {
                    float4 w = wr[c4];
                    acc[c4 * 4 + 0] += fe * w.x;
                    acc[c4 * 4 + 1] += fe * w.y;
                    acc[c4 * 4 + 2] += fe * w.z;
                    acc[c4 * 4 + 3] += fe * w.w;
                }
            }
        }
    }

    float4* o = (float4*)(out + (size_t)i * COUT);
#pragma unroll
    for (int c4 = 0; c4 < COUT / 4; ++c4) {
        float4 r;
        r.x = acc[4 * c4 + 0]; r.y = acc[4 * c4 + 1];
        r.z = acc[4 * c4 + 2]; r.w = acc[4 * c4 + 3];
        r.x = (r.x >= 0.f) ? r.x : NEGS * r.x;
        r.y = (r.y >= 0.f) ? r.y : NEGS * r.y;
        r.z = (r.z >= 0.f) ? r.z : NEGS * r.z;
        r.w = (r.w >= 0.f) ? r.w : NEGS * r.w;
        o[c4] = r;
    }
}

__global__ __launch_bounds__(256) void add_res(float* __restrict__ out,
                                               const float* __restrict__ s, int n4) {
    int i = blockIdx.x * 256 + threadIdx.x;
    if (i < n4) {
        float4 a = ((const float4*)out)[i];
        float4 b = ((const float4*)s)[i];
        a.x += b.x; a.y += b.y; a.z += b.z; a.w += b.w;
        ((float4*)out)[i] = a;
    }
}

extern "C" void kernel_launch(void* const* d_in, const int* in_sizes, int n_in,
                              void* d_out, int out_size, void* d_ws, size_t ws_size,
                              hipStream_t stream) {
    const float* feats = (const float*)d_in[0];
    const int* coords  = (const int*)d_in[1];
    const float* W1    = (const float*)d_in[2];
    const float* W2    = (const float*)d_in[3];
    const float* W3    = (const float*)d_in[4];
    const float* W4    = (const float*)d_in[5];
    const float* gamma = (const float*)d_in[6];
    const float* beta  = (const float*)d_in[7];
    const float* mean  = (const float*)d_in[8];
    const float* var   = (const float*)d_in[9];

    int n = in_sizes[0] / CIN;  // 200000

    char* ws = (char*)d_ws;
    size_t cntBytes  = (size_t)n * sizeof(int);
    size_t entBytes  = (size_t)8 * n * sizeof(int);
    size_t wsBytes   = (size_t)27648 * sizeof(float);
    size_t shBytes   = (size_t)128 * sizeof(float);
    size_t featBytes = (size_t)n * COUT * sizeof(float);
    size_t gridBytes = (size_t)NB * DD * HH * WD * sizeof(int);

    int* cnt133 = (int*)ws;
    int* cnt313 = (int*)(ws + cntBytes);
    int* ent133 = (int*)(ws + 2 * cntBytes);
    int* ent313 = (int*)(ws + 2 * cntBytes + entBytes);
    float* Wsc  = (float*)(ws + 2 * cntBytes + 2 * entBytes);
    float* shv  = (float*)(ws + 2 * cntBytes + 2 * entBytes + wsBytes);
    char* fbase = ws + 2 * cntBytes + 2 * entBytes + wsBytes + shBytes;
    float* s1 = (float*)fbase;                      // conv1 out
    float* s2 = (float*)(fbase + featBytes);        // shortcut
    float* r1 = (float*)(fbase + 2 * featBytes);    // conv3 out
    int* grid = (int*)fbase;  // overlaps s1/s2 region; grid dead after build_nbr

    int nblk = (n + 255) / 256;

    prep_weights<<<(27648 + 255) / 256, 256, 0, stream>>>(
        W1, W2, W3, W4, gamma, beta, mean, var, Wsc, shv);
    hipMemsetAsync(grid, 0xFF, gridBytes, stream);
    scatter_grid<<<nblk, 256, 0, stream>>>(coords, grid, n);
    build_nbr_compact<<<nblk, 256, 0, stream>>>(coords, grid, cnt133, ent133,
                                                cnt313, ent313, n);

    // conv1 (feats->s1, bn0) || conv3 (feats->r1, bn2)
    conv_pair<CIN><<<2 * nblk, 256, 0, stream>>>(
        feats, cnt133, ent133, Wsc + 0,     shv + 0 * COUT, s1,
        feats, cnt313, ent313, Wsc + 13824, shv + 2 * COUT, r1,
        n, nblk);

    // conv2 (s1->s2, bn1) || conv4 (r1->d_out, bn3)
    conv_pair<COUT><<<2 * nblk, 256, 0, stream>>>(
        s1, cnt313, ent313, Wsc + 4608,  shv + 1 * COUT, s2,
        r1, cnt133, ent133, Wsc + 18432, shv + 3 * COUT, (float*)d_out,
        n, nblk);

    // d_out += s2 (resA + shortcut)
    int n4 = n * COUT / 4;
    add_res<<<(n4 + 255) / 256, 256, 0, stream>>>((float*)d_out, s2, n4);
}

// Round 10
// 245.408 us; speedup vs baseline: 1.2132x; 1.0081x over previous
//
#include <hip/hip_runtime.h>

#define NB 2
#define DD 480
#define HH 360
#define WD 32
#define CIN 16
#define COUT 32
#define EPSV 1e-5f
#define NEGS 0.01f

__global__ __launch_bounds__(256) void scatter_grid(const int* __restrict__ coords,
                                                    int* __restrict__ grid, int n) {
    int i = blockIdx.x * 256 + threadIdx.x;
    if (i >= n) return;
    int b = coords[i * 4 + 0];
    int z = coords[i * 4 + 1];
    int y = coords[i * 4 + 2];
    int x = coords[i * 4 + 3];
    grid[(((size_t)b * DD + z) * HH + y) * WD + x] = i;
}

// Compact non-center valid taps per point; emit compacted worklists of
// points that HAVE extras (~13%). List entry: (cnt<<24) | i.
// ent entries: (k<<24) | j.
__global__ __launch_bounds__(256) void build_nbr_compact(
    const int* __restrict__ coords, const int* __restrict__ grid,
    int* __restrict__ ent133, int* __restrict__ list133,
    int* __restrict__ ent313, int* __restrict__ list313,
    int* __restrict__ lcnt, int n) {
    int i = blockIdx.x * 256 + threadIdx.x;
    if (i >= n) return;
    int b = coords[i * 4 + 0];
    int z = coords[i * 4 + 1];
    int y = coords[i * 4 + 2];
    int x = coords[i * 4 + 3];
    size_t base_b = (size_t)b * DD;
    int c1 = 0, c2 = 0;
#pragma unroll
    for (int k = 0; k < 9; ++k) {
        if (k == 4) continue;
        int d0 = k / 3 - 1;  // dy for 133, dz for 313
        int dx = k % 3 - 1;
        int nx = x + dx;
        bool xok = (nx >= 0) && (nx < WD);
        int ny = y + d0;
        if (xok && ny >= 0 && ny < HH) {
            int j = grid[((base_b + z) * HH + ny) * WD + nx];
            if (j >= 0) { ent133[(size_t)c1 * n + i] = (k << 24) | j; ++c1; }
        }
        int nz = z + d0;
        if (xok && nz >= 0 && nz < DD) {
            int j = grid[((base_b + nz) * HH + y) * WD + nx];
            if (j >= 0) { ent313[(size_t)c2 * n + i] = (k << 24) | j; ++c2; }
        }
    }
    if (c1 > 0) { int p = atomicAdd(&lcnt[0], 1); if (p < n) list133[p] = (c1 << 24) | i; }
    if (c2 > 0) { int p = atomicAdd(&lcnt[1], 1); if (p < n) list313[p] = (c2 << 24) | i; }
}

// Fold BN scale into weights once per call; also zeroes lcnt.
// Ws layout (floats): conv1 [9][16][32] @ 0, conv2 [9][32][32] @ 4608,
//                     conv3 [9][16][32] @ 13824, conv4 [9][32][32] @ 18432
__global__ __launch_bounds__(256) void prep_weights(
    const float* __restrict__ W1, const float* __restrict__ W2,
    const float* __restrict__ W3, const float* __restrict__ W4,
    const float* __restrict__ gamma, const float* __restrict__ beta,
    const float* __restrict__ mean, const float* __restrict__ var,
    float* __restrict__ Ws, float* __restrict__ sh, int* __restrict__ lcnt) {
    int t = blockIdx.x * 256 + threadIdx.x;
    if (blockIdx.x == 0 && threadIdx.x < 4) lcnt[threadIdx.x] = 0;
    if (t < 4 * COUT) {
        float s = gamma[t] * rsqrtf(var[t] + EPSV);
        sh[t] = beta[t] - mean[t] * s;
    }
    if (t >= 27648) return;
    const float* src;
    int loc, bn;
    if (t < 4608)       { src = W1; loc = t;         bn = 0; }
    else if (t < 13824) { src = W2; loc = t - 4608;  bn = 1; }
    else if (t < 18432) { src = W3; loc = t - 13824; bn = 2; }
    else                { src = W4; loc = t - 18432; bn = 3; }
    int co = loc & 31;
    float s = gamma[bn * COUT + co] * rsqrtf(var[bn * COUT + co] + EPSV);
    Ws[t] = src[loc] * s;
}

// A: pure dense center-tap pair. No gathers, no divergence.
// Applies lrelu unconditionally; fix_pair inverts it on listed points.
template <int CI>
__global__ __launch_bounds__(256, 4) void center_pair(
    const float* __restrict__ in0, const float* __restrict__ Wc0,
    const float* __restrict__ sh0, float* __restrict__ out0,
    const float* __restrict__ in1, const float* __restrict__ Wc1,
    const float* __restrict__ sh1, float* __restrict__ out1,
    int n, int nblk) {
    __shared__ float Wc[CI * COUT];
    int tid = threadIdx.x;
    bool second = (int)blockIdx.x >= nblk;
    const float* in  = second ? in1 : in0;
    const float* Wg  = second ? Wc1 : Wc0;
    const float* sh  = second ? sh1 : sh0;
    float* out       = second ? out1 : out0;

    {
        const float4* wg4 = (const float4*)Wg;
        float4* wl4 = (float4*)Wc;
        for (int t = tid; t < CI * COUT / 4; t += 256) wl4[t] = wg4[t];
    }
    __syncthreads();

    int ib = second ? (int)blockIdx.x - nblk : (int)blockIdx.x;
    int i = ib * 256 + tid;
    if (i >= n) return;

    float acc[COUT];
    const float4* sh4 = (const float4*)sh;
#pragma unroll
    for (int c4 = 0; c4 < COUT / 4; ++c4) {
        float4 s = sh4[c4];
        acc[c4 * 4 + 0] = s.x; acc[c4 * 4 + 1] = s.y;
        acc[c4 * 4 + 2] = s.z; acc[c4 * 4 + 3] = s.w;
    }

    {
        const float4* f4 = (const float4*)(in + (size_t)i * CI);
#pragma unroll
        for (int q = 0; q < CI / 4; ++q) {
            float4 v = f4[q];
            const float* w = &Wc[q * 4 * COUT];
#pragma unroll
            for (int c4 = 0; c4 < COUT / 4; ++c4) {
                float4 w0 = *(const float4*)&w[0 * COUT + c4 * 4];
                float4 w1 = *(const float4*)&w[1 * COUT + c4 * 4];
                float4 w2 = *(const float4*)&w[2 * COUT + c4 * 4];
                float4 w3 = *(const float4*)&w[3 * COUT + c4 * 4];
                acc[c4 * 4 + 0] += v.x * w0.x + v.y * w1.x + v.z * w2.x + v.w * w3.x;
                acc[c4 * 4 + 1] += v.x * w0.y + v.y * w1.y + v.z * w2.y + v.w * w3.y;
                acc[c4 * 4 + 2] += v.x * w0.z + v.y * w1.z + v.z * w2.z + v.w * w3.z;
                acc[c4 * 4 + 3] += v.x * w0.w + v.y * w1.w + v.z * w2.w + v.w * w3.w;
            }
        }
    }

    float4* o = (float4*)(out + (size_t)i * COUT);
#pragma unroll
    for (int c4 = 0; c4 < COUT / 4; ++c4) {
        float4 r;
        float y0 = acc[4 * c4 + 0], y1 = acc[4 * c4 + 1];
        float y2 = acc[4 * c4 + 2], y3 = acc[4 * c4 + 3];
        r.x = (y0 >= 0.f) ? y0 : NEGS * y0;
        r.y = (y1 >= 0.f) ? y1 : NEGS * y1;
        r.z = (y2 >= 0.f) ? y2 : NEGS * y2;
        r.w = (y3 >= 0.f) ? y3 : NEGS * y3;
        o[c4] = r;
    }
}

// B: fix-up over the compacted list. Invert the lrelu, add extra taps,
// re-apply lrelu. li0/li1 select the lcnt slot for each side (the lists
// are swapped between B13 and B24 — this was the R7-R9 bug).
template <int CI>
__global__ __launch_bounds__(256) void fix_pair(
    const float* __restrict__ in0, const int* __restrict__ list0,
    const int* __restrict__ ent0, const float* __restrict__ Ws0,
    float* __restrict__ out0,
    const float* __restrict__ in1, const int* __restrict__ list1,
    const int* __restrict__ ent1, const float* __restrict__ Ws1,
    float* __restrict__ out1,
    const int* __restrict__ lcnt, int li0, int li1, int n, int nblkB) {
    constexpr int WROW = CI * COUT;
    constexpr int WPAD = WROW + 4;
    __shared__ float Wl[9 * WPAD];
    int tid = threadIdx.x;
    bool second = (int)blockIdx.x >= nblkB;
    const float* in   = second ? in1 : in0;
    const int* list   = second ? list1 : list0;
    const int* ent    = second ? ent1 : ent0;
    const float* Ws   = second ? Ws1 : Ws0;
    float* out        = second ? out1 : out0;
    int lc = lcnt[second ? li1 : li0];
    if (lc > n) lc = n;

    for (int t = tid; t < 9 * WROW / 4; t += 256) {
        int k = t / (WROW / 4);
        int r = t % (WROW / 4);
        ((float4*)&Wl[k * WPAD])[r] = ((const float4*)Ws)[t];
    }
    __syncthreads();

    int ib = second ? (int)blockIdx.x - nblkB : (int)blockIdx.x;
    const float inv = 1.0f / NEGS;
    for (int idx = ib * 256 + tid; idx < lc; idx += nblkB * 256) {
        int le = list[idx];
        int i = le & 0xFFFFFF;
        int cn = le >> 24;
        if ((unsigned)i >= (unsigned)n) continue;
        float acc[COUT];
        const float4* orow = (const float4*)(out + (size_t)i * COUT);
#pragma unroll
        for (int c4 = 0; c4 < COUT / 4; ++c4) {
            float4 a = orow[c4];
            // invert lrelu: recover center-only linear value
            acc[c4 * 4 + 0] = (a.x >= 0.f) ? a.x : inv * a.x;
            acc[c4 * 4 + 1] = (a.y >= 0.f) ? a.y : inv * a.y;
            acc[c4 * 4 + 2] = (a.z >= 0.f) ? a.z : inv * a.z;
            acc[c4 * 4 + 3] = (a.w >= 0.f) ? a.w : inv * a.w;
        }
#pragma unroll 1
        for (int m = 0; m < cn; ++m) {
            int e = ent[(size_t)m * n + i];
            int k = e >> 24;
            int j = e & 0xFFFFFF;
            const float4* g4 = (const float4*)(in + (size_t)j * CI);
            const float* wk = &Wl[k * WPAD];
#pragma unroll
            for (int q = 0; q < CI / 4; ++q) {
                float4 v = g4[q];
#pragma unroll
                for (int e4 = 0; e4 < 4; ++e4) {
                    float fe = (e4 == 0) ? v.x : (e4 == 1) ? v.y : (e4 == 2) ? v.z : v.w;
                    const float4* wr = (const float4*)(wk + (q * 4 + e4) * COUT);
#pragma unroll
                    for (int c4 = 0; c4 < COUT / 4; ++c4) {
                        float4 w = wr[c4];
                        acc[c4 * 4 + 0] += fe * w.x;
                        acc[c4 * 4 + 1] += fe * w.y;
                        acc[c4 * 4 + 2] += fe * w.z;
                        acc[c4 * 4 + 3] += fe * w.w;
                    }
                }
            }
        }
        float4* o = (float4*)(out + (size_t)i * COUT);
#pragma unroll
        for (int c4 = 0; c4 < COUT / 4; ++c4) {
            float4 r;
            float y0 = acc[4 * c4 + 0], y1 = acc[4 * c4 + 1];
            float y2 = acc[4 * c4 + 2], y3 = acc[4 * c4 + 3];
            r.x = (y0 >= 0.f) ? y0 : NEGS * y0;
            r.y = (y1 >= 0.f) ? y1 : NEGS * y1;
            r.z = (y2 >= 0.f) ? y2 : NEGS * y2;
            r.w = (y3 >= 0.f) ? y3 : NEGS * y3;
            o[c4] = r;
        }
    }
}

__global__ __launch_bounds__(256) void add_res(float* __restrict__ out,
                                               const float* __restrict__ s, int n4) {
    int i = blockIdx.x * 256 + threadIdx.x;
    if (i < n4) {
        float4 a = ((const float4*)out)[i];
        float4 b = ((const float4*)s)[i];
        a.x += b.x; a.y += b.y; a.z += b.z; a.w += b.w;
        ((float4*)out)[i] = a;
    }
}

extern "C" void kernel_launch(void* const* d_in, const int* in_sizes, int n_in,
                              void* d_out, int out_size, void* d_ws, size_t ws_size,
                              hipStream_t stream) {
    const float* feats = (const float*)d_in[0];
    const int* coords  = (const int*)d_in[1];
    const float* W1    = (const float*)d_in[2];
    const float* W2    = (const float*)d_in[3];
    const float* W3    = (const float*)d_in[4];
    const float* W4    = (const float*)d_in[5];
    const float* gamma = (const float*)d_in[6];
    const float* beta  = (const float*)d_in[7];
    const float* mean  = (const float*)d_in[8];
    const float* var   = (const float*)d_in[9];

    int n = in_sizes[0] / CIN;  // 200000

    char* ws = (char*)d_ws;
    size_t listBytes = (size_t)n * sizeof(int);
    size_t entBytes  = (size_t)8 * n * sizeof(int);
    size_t wsBytes   = (size_t)27648 * sizeof(float);
    size_t shBytes   = (size_t)128 * sizeof(float);
    size_t featBytes = (size_t)n * COUT * sizeof(float);
    size_t gridBytes = (size_t)NB * DD * HH * WD * sizeof(int);

    char* p = ws;
    int* list133 = (int*)p; p += listBytes;
    int* list313 = (int*)p; p += listBytes;
    int* ent133  = (int*)p; p += entBytes;
    int* ent313  = (int*)p; p += entBytes;
    float* Wsc   = (float*)p; p += wsBytes;
    float* shv   = (float*)p; p += shBytes;
    int* lcnt    = (int*)p; p += 16;
    char* fbase = p;
    float* s1 = (float*)fbase;                      // conv1 out
    float* s2 = (float*)(fbase + featBytes);        // shortcut
    float* r1 = (float*)(fbase + 2 * featBytes);    // conv3 out
    int* grid = (int*)fbase;  // overlaps s1/s2; grid dead before they're written

    int nblk = (n + 255) / 256;
    const int nblkB = 128;  // per side; grid-stride covers list remainder

    prep_weights<<<(27648 + 255) / 256, 256, 0, stream>>>(
        W1, W2, W3, W4, gamma, beta, mean, var, Wsc, shv, lcnt);
    hipMemsetAsync(grid, 0xFF, gridBytes, stream);
    scatter_grid<<<nblk, 256, 0, stream>>>(coords, grid, n);
    build_nbr_compact<<<nblk, 256, 0, stream>>>(coords, grid,
        ent133, list133, ent313, list313, lcnt, n);

    const float* Wc1 = Wsc + 0     + 4 * CIN * COUT;
    const float* Wc2 = Wsc + 4608  + 4 * COUT * COUT;
    const float* Wc3 = Wsc + 13824 + 4 * CIN * COUT;
    const float* Wc4 = Wsc + 18432 + 4 * COUT * COUT;

    // A13: conv1 center (feats->s1) || conv3 center (feats->r1)
    center_pair<CIN><<<2 * nblk, 256, 0, stream>>>(
        feats, Wc1, shv + 0 * COUT, s1,
        feats, Wc3, shv + 2 * COUT, r1, n, nblk);
    // B13: fix conv1 (list133 -> lcnt[0]) || fix conv3 (list313 -> lcnt[1])
    fix_pair<CIN><<<2 * nblkB, 256, 0, stream>>>(
        feats, list133, ent133, Wsc + 0,     s1,
        feats, list313, ent313, Wsc + 13824, r1, lcnt, 0, 1, n, nblkB);

    // A24: conv2 center (s1->s2) || conv4 center (r1->d_out)
    center_pair<COUT><<<2 * nblk, 256, 0, stream>>>(
        s1, Wc2, shv + 1 * COUT, s2,
        r1, Wc4, shv + 3 * COUT, (float*)d_out, n, nblk);
    // B24: fix conv2 (list313 -> lcnt[1]) || fix conv4 (list133 -> lcnt[0])
    fix_pair<COUT><<<2 * nblkB, 256, 0, stream>>>(
        s1, list313, ent313, Wsc + 4608,  s2,
        r1, list133, ent133, Wsc + 18432, (float*)d_out, lcnt, 1, 0, n, nblkB);

    // d_out += s2 (resA + shortcut)
    int n4 = n * COUT / 4;
    add_res<<<(n4 + 255) / 256, 256, 0, stream>>>((float*)d_out, s2, n4);
}